// Round 5
// baseline (566.114 us; speedup 1.0000x reference)
//
#include <hip/hip_runtime.h>
#include <math.h>

#define DD   128
#define SS   16
#define NL   2
#define GDIM 14
#define NN   8

typedef short  s16x8 __attribute__((ext_vector_type(8)));
typedef float  f32x4 __attribute__((ext_vector_type(4)));
typedef unsigned short ushort_t;

// ws layout:
//   ushort region:
//     inWt  [128 col][32 k]        @ 0       (4096)
//     dtWt  [2 l][256 col][128 k]  @ 4096    (65536)
//     bcWt  [2 l][64 col][128 k]   @ 69632   (16384)
//     outWt [2 l][128 col][256 k]  @ 86016   (65536)
//   float region @ ushort offset 151552 (byte 303104):
//     A_pre [l*2+dir][16 s][128 d]  @ f0      (8192)   = -exp(Alog)*log2(e)
//     peb   [8 n][128 d]            @ f8192   (1024)   = inB[d] + PE(n,d)
//     te    [B][128 d]              @ f9216   (B*128)  = silu(t W1+b1) W2 + b2
#define WS_INW   0
#define WS_DTW   4096
#define WS_BCW   69632
#define WS_OUTW  86016
#define WS_USH   151552
#define WS_AFLT  8192
#define WS_PEB   8192
#define WS_TE    9216

#if __has_builtin(__builtin_amdgcn_exp2f)
#define EXP2(x) __builtin_amdgcn_exp2f(x)
#else
#define EXP2(x) exp2f(x)
#endif

__device__ __forceinline__ unsigned short f2bf(float f) {
    unsigned u = __float_as_uint(f);
    u += 0x7fffu + ((u >> 16) & 1u);     // RNE
    return (unsigned short)(u >> 16);
}

__device__ __forceinline__ float softplus_fast(float x) {
    return fmaxf(x, 0.f) + __logf(1.f + __expf(-fabsf(x)));
}
__device__ __forceinline__ float softplus_precise(float x) {
    return fmaxf(x, 0.f) + log1pf(expf(-fabsf(x)));
}

extern "C" __global__ void __launch_bounds__(256)
prep_weights(const float* __restrict__ inW, const float* __restrict__ dtW,
             const float* __restrict__ BW,  const float* __restrict__ CW,
             const float* __restrict__ outW, const float* __restrict__ Alog,
             const float* __restrict__ tstamp, const float* __restrict__ inB,
             const float* __restrict__ t_arr,
             const float* __restrict__ teW1, const float* __restrict__ teB1,
             const float* __restrict__ teW2, const float* __restrict__ teB2,
             int Bcnt, ushort_t* __restrict__ ws)
{
    float* wsf = (float*)(ws + WS_USH);
    int i = blockIdx.x * 256 + threadIdx.x;
    if (i < 4096) {                               // inWt [d][k]
        int d = i >> 5, k = i & 31;
        ws[WS_INW + i] = (k < GDIM) ? f2bf(inW[k * DD + d]) : (ushort_t)0;
        return;
    }
    i -= 4096;
    if (i < 65536) {                              // dtWt [l][col][k]
        int l = i >> 15, r = i & 32767;
        int col = r >> 7, k = r & 127;
        int dir = col >> 7, d = col & 127;
        ws[WS_DTW + i] = f2bf(dtW[((size_t)(l * 2 + dir) * DD + k) * DD + d]);
        return;
    }
    i -= 65536;
    if (i < 16384) {                              // bcWt [l][col][k]
        int l = i >> 13, r = i & 8191;
        int col = r >> 7, k = r & 127;
        int dir = col >> 5, which = (col >> 4) & 1, s = col & 15;
        const float* Wsrc = which ? CW : BW;
        ws[WS_BCW + i] = f2bf(Wsrc[((size_t)(l * 2 + dir) * DD + k) * SS + s]);
        return;
    }
    i -= 16384;
    if (i < 65536) {                              // outWt [l][col][k]
        int l = i >> 15, r = i & 32767;
        int col = r >> 8, k = r & 255;
        ws[WS_OUTW + i] = f2bf(outW[((size_t)l * 2 * DD + k) * DD + col]);
        return;
    }
    i -= 65536;
    if (i < WS_AFLT) {                            // A_pre [ld][s][d]
        int ld = i >> 11, r = i & 2047;
        int s = r >> 7, d = r & 127;
        wsf[i] = -expf(Alog[((size_t)ld * DD + d) * SS + s]) * 1.44269504088896f;
        return;
    }
    i -= WS_AFLT;
    if (i < 1024) {                               // peb [n][d] = inB + PE
        int n = i >> 7, d = i & 127;
        int j = d & 63;
        float freq = expf(-logf(10000.f) * (float)j * (1.f / 64.f));
        float ang = tstamp[n] * freq;
        wsf[WS_PEB + i] = inB[d] + ((d < 64) ? sinf(ang) : cosf(ang));
        return;
    }
    i -= 1024;
    if (i < Bcnt * 128) {                         // te [b][d]
        int b = i >> 7, d = i & 127;
        float tv = t_arr[b];
        float acc = teB2[d];
        for (int k = 0; k < DD; ++k) {
            float u = fmaf(tv, teW1[k], teB1[k]);
            float s = u / (1.f + expf(-u));
            acc = fmaf(s, teW2[k * DD + d], acc);
        }
        wsf[WS_TE + i] = acc;
    }
}

extern "C" __global__ void __launch_bounds__(256, 6)
ssm_mfma(const float* __restrict__ xyz, const float* __restrict__ scl,
         const float* __restrict__ rotp, const float* __restrict__ opa,
         const float* __restrict__ colp,
         const float* __restrict__ t_arr,
         const float* __restrict__ lnG, const float* __restrict__ lnB,
         const float* __restrict__ dtB,
         const float* __restrict__ Dskp,
         const float* __restrict__ outB,
         const float* __restrict__ opW, const float* __restrict__ opB,
         const ushort_t* __restrict__ wsu,
         float* __restrict__ out, int M, int Pb)
{
    const int t    = threadIdx.x;
    const int lane = t & 63;
    const int wv   = t >> 6;          // wave 0..3
    const int d    = t & 127;         // channel
    const int p    = t >> 7;          // point-in-block 0..1
    const int m0   = blockIdx.x * 2;
    const int m    = m0 + p;
    const int r16  = lane & 15;
    const int kg   = lane >> 4;

    // arenaA (8448 B): Xs bf16 [16 rows @264 ushort] ∪ pres f32 [16][132] ∪ bcres f32 [16][68]
    // arenaB (16640 B): dtres f32 [16][260] ∪ Ys bf16 [16 rows @520 ushort] ∪ epilogue hi2/outg
    __shared__ float arenaA[16][132];
    __shared__ float arenaB[16][260];
    __shared__ float red  [4][2][NN];

    float (*pres)[132] = arenaA;
    ushort_t* XsU = (ushort_t*)&arenaA[0][0];     // [row*264 + k]
    float (*bcres)[68] = (float(*)[68])&arenaA[0][0];
    float (*dtres)[260] = arenaB;
    ushort_t* YsU = (ushort_t*)&arenaB[0][0];     // [row*520 + c]

    const ushort_t* inWt  = wsu + WS_INW;
    const ushort_t* dtWt  = wsu + WS_DTW;
    const ushort_t* bcWt  = wsu + WS_BCW;
    const ushort_t* outWt = wsu + WS_OUTW;
    const float*    wsf   = (const float*)(wsu + WS_USH);
    const float*    Apre  = wsf;
    const float*    peb   = wsf + WS_PEB;
    const float*    te    = wsf + WS_TE;

    // ---- stage params into Xs (bf16), k padded to 32 with zeros ----
    for (int idx = t; idx < 16 * 32; idx += 256) {
        const int row = idx >> 5, k = idx & 31;
        const int pp = row >> 3, n = row & 7;
        const int mm = m0 + pp;
        float v = 0.f;
        if (k < GDIM && mm < M) {
            if (k < 3)       v = xyz [((size_t)n * M + mm) * 3 + k];
            else if (k < 6)  v = scl [((size_t)n * M + mm) * 3 + (k - 3)];
            else if (k < 10) v = rotp[((size_t)n * M + mm) * 4 + (k - 6)];
            else if (k < 11) v = opa [ (size_t)n * M + mm];
            else             v = colp[((size_t)n * M + mm) * 3 + (k - 11)];
        }
        XsU[row * 264 + k] = f2bf(v);
    }
    __syncthreads();                                       // S0

    // ---- in-projection MFMA (reads Xs, writes pres — same arena: frag first) ----
    {
        const s16x8 a = *(const s16x8*)&XsU[r16 * 264 + kg * 8];
        __syncthreads();                                   // S0b
        #pragma unroll
        for (int ti = 0; ti < 2; ++ti) {
            const int col = (wv * 2 + ti) * 16 + r16;
            const s16x8 b = *(const s16x8*)&inWt[col * 32 + kg * 8];
            f32x4 acc = {0.f, 0.f, 0.f, 0.f};
            acc = __builtin_amdgcn_mfma_f32_16x16x32_bf16(a, b, acc, 0, 0, 0);
            #pragma unroll
            for (int j = 0; j < 4; ++j) pres[kg * 4 + j][col] = acc[j];
        }
    }
    __syncthreads();                                       // S0c

    // ---- h = in-proj + (bias + positional encoding) table ----
    float h[NN];
    #pragma unroll
    for (int n = 0; n < NN; ++n)
        h[n] = pres[p * 8 + n][d] + peb[n * DD + d];

    // ================= layers =================
    for (int l = 0; l < NL; ++l) {
        // ---- P0: LayerNorm reduce ----
        float sum[NN], sq[NN];
        #pragma unroll
        for (int n = 0; n < NN; ++n) { sum[n] = h[n]; sq[n] = h[n] * h[n]; }
        #pragma unroll
        for (int off = 32; off > 0; off >>= 1) {
            #pragma unroll
            for (int n = 0; n < NN; ++n) {
                sum[n] += __shfl_xor(sum[n], off);
                sq[n]  += __shfl_xor(sq[n],  off);
            }
        }
        if (lane == 0) {
            #pragma unroll
            for (int n = 0; n < NN; ++n) { red[wv][0][n] = sum[n]; red[wv][1][n] = sq[n]; }
        }
        __syncthreads();                                   // S1

        // ---- P1: xn + write bf16 to Xs ----
        float xn[NN];
        {
            const float gg = lnG[l * DD + d], bb = lnB[l * DD + d];
            #pragma unroll
            for (int n = 0; n < NN; ++n) {
                const float s0 = red[2 * p][0][n] + red[2 * p + 1][0][n];
                const float s1 = red[2 * p][1][n] + red[2 * p + 1][1][n];
                const float mean = s0 * (1.f / 128.f);
                float var = s1 * (1.f / 128.f) - mean * mean;
                const float inv = rsqrtf(fmaxf(var, 0.f) + 1e-5f);
                xn[n] = fmaf((h[n] - mean) * inv, gg, bb);
                XsU[(p * 8 + n) * 264 + d] = f2bf(xn[n]);
            }
        }
        __syncthreads();                                   // S2

        // ---- P2: MFMA dt (256 cols, -> dtres) + B/C (64 cols, -> bcres overlay) ----
        {
            s16x8 a[4];
            #pragma unroll
            for (int kc = 0; kc < 4; ++kc)
                a[kc] = *(const s16x8*)&XsU[r16 * 264 + kc * 32 + kg * 8];
            __syncthreads();                               // S2b: all Xs reads done (bcres overlays Xs)

            const ushort_t* dtl = dtWt + l * 32768;
            #pragma unroll
            for (int ti = 0; ti < 4; ++ti) {
                const int col = (wv * 4 + ti) * 16 + r16;
                f32x4 acc = {0.f, 0.f, 0.f, 0.f};
                #pragma unroll
                for (int kc = 0; kc < 4; ++kc) {
                    const s16x8 b = *(const s16x8*)&dtl[col * 128 + kc * 32 + kg * 8];
                    acc = __builtin_amdgcn_mfma_f32_16x16x32_bf16(a[kc], b, acc, 0, 0, 0);
                }
                #pragma unroll
                for (int j = 0; j < 4; ++j) dtres[kg * 4 + j][col] = acc[j];
            }
            const ushort_t* bcl = bcWt + l * 8192;
            {
                const int col = wv * 16 + r16;
                f32x4 acc = {0.f, 0.f, 0.f, 0.f};
                #pragma unroll
                for (int kc = 0; kc < 4; ++kc) {
                    const s16x8 b = *(const s16x8*)&bcl[col * 128 + kc * 32 + kg * 8];
                    acc = __builtin_amdgcn_mfma_f32_16x16x32_bf16(a[kc], b, acc, 0, 0, 0);
                }
                #pragma unroll
                for (int j = 0; j < 4; ++j) bcres[kg * 4 + j][col] = acc[j];
            }
        }
        __syncthreads();                                   // S3

        // ---- P3a: softplus(dt) into regs ----
        float dtv[2][NN];
        #pragma unroll
        for (int dir = 0; dir < 2; ++dir) {
            const float db = dtB[(l * 2 + dir) * DD + d];
            #pragma unroll
            for (int n = 0; n < NN; ++n)
                dtv[dir][n] = softplus_fast(dtres[p * 8 + n][dir * 128 + d] + db);
        }
        __syncthreads();                                   // S3b: dtres reads done (Ys overlays)

        // ---- P3b: SSM scan, write y bf16 into Ys ----
        #pragma unroll
        for (int dir = 0; dir < 2; ++dir) {
            const float* Ap = Apre + (size_t)(l * 2 + dir) * SS * DD + d;
            float Ar[SS];
            #pragma unroll
            for (int s = 0; s < SS; ++s) Ar[s] = Ap[s * DD];
            const float dsk = Dskp[(l * 2 + dir) * DD + d];
            float st[SS];
            #pragma unroll
            for (int s = 0; s < SS; ++s) st[s] = 0.f;
            #pragma unroll
            for (int t8 = 0; t8 < NN; ++t8) {
                const int n = dir ? (NN - 1 - t8) : t8;
                const float dtc = dtv[dir][n];
                const float xv  = xn[n];
                const float dx  = dtc * xv;
                float y = dsk * xv;
                const float* base = &bcres[p * 8 + n][dir * 32];
                #pragma unroll
                for (int s4 = 0; s4 < SS; s4 += 4) {
                    const float4 Bv = *(const float4*)&base[s4];
                    const float4 Cv = *(const float4*)&base[16 + s4];
                    st[s4+0] = fmaf(EXP2(Ar[s4+0] * dtc), st[s4+0], dx * Bv.x);
                    y = fmaf(st[s4+0], Cv.x, y);
                    st[s4+1] = fmaf(EXP2(Ar[s4+1] * dtc), st[s4+1], dx * Bv.y);
                    y = fmaf(st[s4+1], Cv.y, y);
                    st[s4+2] = fmaf(EXP2(Ar[s4+2] * dtc), st[s4+2], dx * Bv.z);
                    y = fmaf(st[s4+2], Cv.z, y);
                    st[s4+3] = fmaf(EXP2(Ar[s4+3] * dtc), st[s4+3], dx * Bv.w);
                    y = fmaf(st[s4+3], Cv.w, y);
                }
                YsU[(p * 8 + n) * 520 + dir * 128 + d] = f2bf(y);
            }
        }
        __syncthreads();                                   // S4

        // ---- P4: MFMA out-projection: C[16x128] = y[16x256] @ outW ----
        {
            s16x8 a[8];
            #pragma unroll
            for (int kc = 0; kc < 8; ++kc)
                a[kc] = *(const s16x8*)&YsU[r16 * 520 + kc * 32 + kg * 8];
            const ushort_t* ol = outWt + l * 32768;
            #pragma unroll
            for (int ti = 0; ti < 2; ++ti) {
                const int col = (wv * 2 + ti) * 16 + r16;
                f32x4 acc = {0.f, 0.f, 0.f, 0.f};
                #pragma unroll
                for (int kc = 0; kc < 8; ++kc) {
                    const s16x8 b = *(const s16x8*)&ol[col * 256 + kc * 32 + kg * 8];
                    acc = __builtin_amdgcn_mfma_f32_16x16x32_bf16(a[kc], b, acc, 0, 0, 0);
                }
                #pragma unroll
                for (int j = 0; j < 4; ++j) pres[kg * 4 + j][col] = acc[j];
            }
        }
        __syncthreads();                                   // S5

        // ---- P5: residual ----
        {
            const float ob = outB[l * DD + d];
            #pragma unroll
            for (int n = 0; n < NN; ++n) h[n] += pres[p * 8 + n][d] + ob;
        }
    }

    // ---- time interpolation + te (precomputed) ----
    const int mc = (m < M) ? m : (M - 1);
    const int bidx = mc / Pb;
    const float tv = t_arr[bidx];
    const float tn = tv * (float)(NN - 1);
    int il = (int)floorf(tn);
    il = il < 0 ? 0 : (il > NN - 2 ? NN - 2 : il);
    const float alpha = tn - (float)il;
    float hlow = 0.f, hhigh = 0.f;
    #pragma unroll
    for (int n = 0; n < NN; ++n) {
        if (n == il)     hlow  = h[n];
        if (n == il + 1) hhigh = h[n];
    }
    float hi = (1.f - alpha) * hlow + alpha * hhigh + te[bidx * DD + d];

    // epilogue buffers overlay arenaB (free after S5): hi2 [2][132] @0, outg [2][16] @264
    float* epi = &arenaB[0][0];
    epi[p * 132 + d] = hi;
    __syncthreads();

    // ---- final 14-wide projection ----
    if (d < GDIM * 8) {
        const int g = d >> 3, j = d & 7;
        float part = 0.f;
        #pragma unroll
        for (int q = 0; q < 16; ++q)
            part = fmaf(epi[p * 132 + j + 8 * q], opW[(j + 8 * q) * GDIM + g], part);
        part += __shfl_xor(part, 4);
        part += __shfl_xor(part, 2);
        part += __shfl_xor(part, 1);
        if (j == 0) epi[264 + p * 16 + g] = part + opB[g];
    }
    __syncthreads();

    // ---- post-process + store ----
    if (d < GDIM && m < M) {
        const int g = d;
        const float v = epi[264 + p * 16 + g];
        float r;
        if (g < 3)        r = v;
        else if (g < 6)   r = softplus_precise(v);
        else if (g < 10) {
            const float q0 = epi[264 + p * 16 + 6], q1 = epi[264 + p * 16 + 7];
            const float q2 = epi[264 + p * 16 + 8], q3 = epi[264 + p * 16 + 9];
            const float nrm = sqrtf(fmaf(q0,q0, fmaf(q1,q1, fmaf(q2,q2, q3*q3))));
            r = v / fmaxf(nrm, 1e-12f);
        } else {
            r = 1.f / (1.f + expf(-v));
        }
        out[(size_t)m * GDIM + g] = r;
    }
}

extern "C" void kernel_launch(void* const* d_in, const int* in_sizes, int n_in,
                              void* d_out, int out_size, void* d_ws, size_t ws_size,
                              hipStream_t stream) {
    const float* xyz   = (const float*)d_in[0];
    const float* scl   = (const float*)d_in[1];
    const float* rotp  = (const float*)d_in[2];
    const float* opa   = (const float*)d_in[3];
    const float* colp  = (const float*)d_in[4];
    const float* t_arr = (const float*)d_in[5];
    const float* tstmp = (const float*)d_in[6];
    const float* inW   = (const float*)d_in[7];
    const float* inB   = (const float*)d_in[8];
    const float* lnG   = (const float*)d_in[9];
    const float* lnB   = (const float*)d_in[10];
    const float* dtW   = (const float*)d_in[11];
    const float* dtB   = (const float*)d_in[12];
    const float* BW    = (const float*)d_in[13];
    const float* CW    = (const float*)d_in[14];
    const float* Alog  = (const float*)d_in[15];
    const float* Dskp  = (const float*)d_in[16];
    const float* outW  = (const float*)d_in[17];
    const float* outB  = (const float*)d_in[18];
    const float* teW1  = (const float*)d_in[19];
    const float* teB1  = (const float*)d_in[20];
    const float* teW2  = (const float*)d_in[21];
    const float* teB2  = (const float*)d_in[22];
    const float* opW   = (const float*)d_in[23];
    const float* opB   = (const float*)d_in[24];

    const int N  = in_sizes[6];            // 8
    const int M  = in_sizes[3] / N;        // B*P
    const int B  = in_sizes[5];
    const int Pb = M / B;
    (void)out_size; (void)n_in;

    ushort_t* wsu = (ushort_t*)d_ws;
    const int prep_elems = WS_USH + WS_AFLT + 1024 + B * 128;
    hipLaunchKernelGGL(prep_weights, dim3((prep_elems + 255) / 256), dim3(256), 0, stream,
                       inW, dtW, BW, CW, outW, Alog, tstmp, inB, t_arr,
                       teW1, teB1, teW2, teB2, B, wsu);
    hipLaunchKernelGGL(ssm_mfma, dim3((M + 1) / 2), dim3(256), 0, stream,
                       xyz, scl, rotp, opa, colp, t_arr,
                       lnG, lnB, dtB, Dskp, outB, opW, opB,
                       wsu, (float*)d_out, M, Pb);
}

// Round 6
// 491.002 us; speedup vs baseline: 1.1530x; 1.1530x over previous
//
#include <hip/hip_runtime.h>
#include <math.h>

#define DD   128
#define SS   16
#define NL   2
#define GDIM 14
#define NN   8

typedef short  s16x8 __attribute__((ext_vector_type(8)));
typedef float  f32x4 __attribute__((ext_vector_type(4)));
typedef unsigned short ushort_t;

// ws layout:
//   ushort region:
//     inWt  [128 col][32 k]        @ 0       (4096)
//     dtWt  [2 l][256 col][128 k]  @ 4096    (65536)
//     bcWt  [2 l][64 col][128 k]   @ 69632   (16384)
//     outWt [2 l][128 col][256 k]  @ 86016   (65536)
//   float region @ ushort offset 151552 (byte 303104):
//     A_pre [l*2+dir][16 s][128 d]  @ f0      (8192)   = -exp(Alog)*log2(e)
//     peb   [8 n][128 d]            @ f8192   (1024)   = inB[d] + PE(n,d)
//     te    [B][128 d]              @ f9216   (B*128)  = silu(t W1+b1) W2 + b2
#define WS_INW   0
#define WS_DTW   4096
#define WS_BCW   69632
#define WS_OUTW  86016
#define WS_USH   151552
#define WS_AFLT  8192
#define WS_PEB   8192
#define WS_TE    9216

#if __has_builtin(__builtin_amdgcn_exp2f)
#define EXP2(x) __builtin_amdgcn_exp2f(x)
#else
#define EXP2(x) exp2f(x)
#endif

__device__ __forceinline__ unsigned short f2bf(float f) {
    unsigned u = __float_as_uint(f);
    u += 0x7fffu + ((u >> 16) & 1u);     // RNE
    return (unsigned short)(u >> 16);
}

__device__ __forceinline__ float softplus_fast(float x) {
    return fmaxf(x, 0.f) + __logf(1.f + __expf(-fabsf(x)));
}
__device__ __forceinline__ float softplus_precise(float x) {
    return fmaxf(x, 0.f) + log1pf(expf(-fabsf(x)));
}

extern "C" __global__ void __launch_bounds__(256)
prep_weights(const float* __restrict__ inW, const float* __restrict__ dtW,
             const float* __restrict__ BW,  const float* __restrict__ CW,
             const float* __restrict__ outW, const float* __restrict__ Alog,
             const float* __restrict__ tstamp, const float* __restrict__ inB,
             const float* __restrict__ t_arr,
             const float* __restrict__ teW1, const float* __restrict__ teB1,
             const float* __restrict__ teW2, const float* __restrict__ teB2,
             int Bcnt, ushort_t* __restrict__ ws)
{
    float* wsf = (float*)(ws + WS_USH);
    int i = blockIdx.x * 256 + threadIdx.x;
    if (i < 4096) {                               // inWt [d][k]
        int d = i >> 5, k = i & 31;
        ws[WS_INW + i] = (k < GDIM) ? f2bf(inW[k * DD + d]) : (ushort_t)0;
        return;
    }
    i -= 4096;
    if (i < 65536) {                              // dtWt [l][col][k]
        int l = i >> 15, r = i & 32767;
        int col = r >> 7, k = r & 127;
        int dir = col >> 7, d = col & 127;
        ws[WS_DTW + i] = f2bf(dtW[((size_t)(l * 2 + dir) * DD + k) * DD + d]);
        return;
    }
    i -= 65536;
    if (i < 16384) {                              // bcWt [l][col][k]
        int l = i >> 13, r = i & 8191;
        int col = r >> 7, k = r & 127;
        int dir = col >> 5, which = (col >> 4) & 1, s = col & 15;
        const float* Wsrc = which ? CW : BW;
        ws[WS_BCW + i] = f2bf(Wsrc[((size_t)(l * 2 + dir) * DD + k) * SS + s]);
        return;
    }
    i -= 16384;
    if (i < 65536) {                              // outWt [l][col][k]
        int l = i >> 15, r = i & 32767;
        int col = r >> 8, k = r & 255;
        ws[WS_OUTW + i] = f2bf(outW[((size_t)l * 2 * DD + k) * DD + col]);
        return;
    }
    i -= 65536;
    if (i < WS_AFLT) {                            // A_pre [ld][s][d]
        int ld = i >> 11, r = i & 2047;
        int s = r >> 7, d = r & 127;
        wsf[i] = -expf(Alog[((size_t)ld * DD + d) * SS + s]) * 1.44269504088896f;
        return;
    }
    i -= WS_AFLT;
    if (i < 1024) {                               // peb [n][d] = inB + PE
        int n = i >> 7, d = i & 127;
        int j = d & 63;
        float freq = expf(-logf(10000.f) * (float)j * (1.f / 64.f));
        float ang = tstamp[n] * freq;
        wsf[WS_PEB + i] = inB[d] + ((d < 64) ? sinf(ang) : cosf(ang));
        return;
    }
    i -= 1024;
    if (i < Bcnt * 128) {                         // te [b][d]
        int b = i >> 7, d = i & 127;
        float tv = t_arr[b];
        float acc = teB2[d];
        for (int k = 0; k < DD; ++k) {
            float u = fmaf(tv, teW1[k], teB1[k]);
            float s = u / (1.f + expf(-u));
            acc = fmaf(s, teW2[k * DD + d], acc);
        }
        wsf[WS_TE + i] = acc;
    }
}

extern "C" __global__ void __launch_bounds__(256, 4)
ssm_mfma(const float* __restrict__ xyz, const float* __restrict__ scl,
         const float* __restrict__ rotp, const float* __restrict__ opa,
         const float* __restrict__ colp,
         const float* __restrict__ t_arr,
         const float* __restrict__ lnG, const float* __restrict__ lnB,
         const float* __restrict__ dtB,
         const float* __restrict__ Dskp,
         const float* __restrict__ outB,
         const float* __restrict__ opW, const float* __restrict__ opB,
         const ushort_t* __restrict__ wsu,
         float* __restrict__ out, int M, int Pb)
{
    const int t    = threadIdx.x;
    const int lane = t & 63;
    const int wv   = t >> 6;          // wave 0..3
    const int d    = t & 127;         // channel
    const int p    = t >> 7;          // point-in-block 0..1
    const int m0   = blockIdx.x * 2;
    const int m    = m0 + p;
    const int r16  = lane & 15;
    const int kg   = lane >> 4;

    // arenaA (8448 B): Xs bf16 [16 rows @264 ushort] ∪ pres f32 [16][132] ∪ bcres f32 [16][68]
    // arenaB (16640 B): dtres f32 [16][260] ∪ Ys bf16 [16 rows @520 ushort] ∪ epilogue hi2/outg
    __shared__ float arenaA[16][132];
    __shared__ float arenaB[16][260];
    __shared__ float red  [4][2][NN];

    float (*pres)[132] = arenaA;
    ushort_t* XsU = (ushort_t*)&arenaA[0][0];     // [row*264 + k]
    float (*bcres)[68] = (float(*)[68])&arenaA[0][0];
    float (*dtres)[260] = arenaB;
    ushort_t* YsU = (ushort_t*)&arenaB[0][0];     // [row*520 + c]

    const ushort_t* inWt  = wsu + WS_INW;
    const ushort_t* dtWt  = wsu + WS_DTW;
    const ushort_t* bcWt  = wsu + WS_BCW;
    const ushort_t* outWt = wsu + WS_OUTW;
    const float*    wsf   = (const float*)(wsu + WS_USH);
    const float*    Apre  = wsf;
    const float*    peb   = wsf + WS_PEB;
    const float*    te    = wsf + WS_TE;

    // ---- stage params into Xs (bf16), k padded to 32 with zeros ----
    for (int idx = t; idx < 16 * 32; idx += 256) {
        const int row = idx >> 5, k = idx & 31;
        const int pp = row >> 3, n = row & 7;
        const int mm = m0 + pp;
        float v = 0.f;
        if (k < GDIM && mm < M) {
            if (k < 3)       v = xyz [((size_t)n * M + mm) * 3 + k];
            else if (k < 6)  v = scl [((size_t)n * M + mm) * 3 + (k - 3)];
            else if (k < 10) v = rotp[((size_t)n * M + mm) * 4 + (k - 6)];
            else if (k < 11) v = opa [ (size_t)n * M + mm];
            else             v = colp[((size_t)n * M + mm) * 3 + (k - 11)];
        }
        XsU[row * 264 + k] = f2bf(v);
    }
    __syncthreads();                                       // S0

    // ---- in-projection MFMA (reads Xs, writes pres — same arena: frag first) ----
    {
        const s16x8 a = *(const s16x8*)&XsU[r16 * 264 + kg * 8];
        __syncthreads();                                   // S0b
        #pragma unroll
        for (int ti = 0; ti < 2; ++ti) {
            const int col = (wv * 2 + ti) * 16 + r16;
            const s16x8 b = *(const s16x8*)&inWt[col * 32 + kg * 8];
            f32x4 acc = {0.f, 0.f, 0.f, 0.f};
            acc = __builtin_amdgcn_mfma_f32_16x16x32_bf16(a, b, acc, 0, 0, 0);
            #pragma unroll
            for (int j = 0; j < 4; ++j) pres[kg * 4 + j][col] = acc[j];
        }
    }
    __syncthreads();                                       // S0c

    // ---- h = in-proj + (bias + positional encoding) table ----
    float h[NN];
    #pragma unroll
    for (int n = 0; n < NN; ++n)
        h[n] = pres[p * 8 + n][d] + peb[n * DD + d];

    // ================= layers =================
    for (int l = 0; l < NL; ++l) {
        // ---- P0: LayerNorm reduce ----
        float sum[NN], sq[NN];
        #pragma unroll
        for (int n = 0; n < NN; ++n) { sum[n] = h[n]; sq[n] = h[n] * h[n]; }
        #pragma unroll
        for (int off = 32; off > 0; off >>= 1) {
            #pragma unroll
            for (int n = 0; n < NN; ++n) {
                sum[n] += __shfl_xor(sum[n], off);
                sq[n]  += __shfl_xor(sq[n],  off);
            }
        }
        if (lane == 0) {
            #pragma unroll
            for (int n = 0; n < NN; ++n) { red[wv][0][n] = sum[n]; red[wv][1][n] = sq[n]; }
        }
        __syncthreads();                                   // S1

        // ---- P1: xn + write bf16 to Xs ----
        float xn[NN];
        {
            const float gg = lnG[l * DD + d], bb = lnB[l * DD + d];
            #pragma unroll
            for (int n = 0; n < NN; ++n) {
                const float s0 = red[2 * p][0][n] + red[2 * p + 1][0][n];
                const float s1 = red[2 * p][1][n] + red[2 * p + 1][1][n];
                const float mean = s0 * (1.f / 128.f);
                float var = s1 * (1.f / 128.f) - mean * mean;
                const float inv = rsqrtf(fmaxf(var, 0.f) + 1e-5f);
                xn[n] = fmaf((h[n] - mean) * inv, gg, bb);
                XsU[(p * 8 + n) * 264 + d] = f2bf(xn[n]);
            }
        }
        __syncthreads();                                   // S2

        // ---- P2: MFMA dt (256 cols, -> dtres) + B/C (64 cols, -> bcres overlay) ----
        {
            s16x8 a[4];
            #pragma unroll
            for (int kc = 0; kc < 4; ++kc)
                a[kc] = *(const s16x8*)&XsU[r16 * 264 + kc * 32 + kg * 8];
            __syncthreads();                               // S2b: all Xs reads done (bcres overlays Xs)

            const ushort_t* dtl = dtWt + l * 32768;
            #pragma unroll
            for (int ti = 0; ti < 4; ++ti) {
                const int col = (wv * 4 + ti) * 16 + r16;
                f32x4 acc = {0.f, 0.f, 0.f, 0.f};
                #pragma unroll
                for (int kc = 0; kc < 4; ++kc) {
                    const s16x8 b = *(const s16x8*)&dtl[col * 128 + kc * 32 + kg * 8];
                    acc = __builtin_amdgcn_mfma_f32_16x16x32_bf16(a[kc], b, acc, 0, 0, 0);
                }
                #pragma unroll
                for (int j = 0; j < 4; ++j) dtres[kg * 4 + j][col] = acc[j];
            }
            const ushort_t* bcl = bcWt + l * 8192;
            {
                const int col = wv * 16 + r16;
                f32x4 acc = {0.f, 0.f, 0.f, 0.f};
                #pragma unroll
                for (int kc = 0; kc < 4; ++kc) {
                    const s16x8 b = *(const s16x8*)&bcl[col * 128 + kc * 32 + kg * 8];
                    acc = __builtin_amdgcn_mfma_f32_16x16x32_bf16(a[kc], b, acc, 0, 0, 0);
                }
                #pragma unroll
                for (int j = 0; j < 4; ++j) bcres[kg * 4 + j][col] = acc[j];
            }
        }
        __syncthreads();                                   // S3

        // ---- P3a: softplus(dt) into regs ----
        float dtv[2][NN];
        #pragma unroll
        for (int dir = 0; dir < 2; ++dir) {
            const float db = dtB[(l * 2 + dir) * DD + d];
            #pragma unroll
            for (int n = 0; n < NN; ++n)
                dtv[dir][n] = softplus_fast(dtres[p * 8 + n][dir * 128 + d] + db);
        }
        __syncthreads();                                   // S3b: dtres reads done (Ys overlays)

        // ---- P3b: SSM scan, write y bf16 into Ys ----
        #pragma unroll
        for (int dir = 0; dir < 2; ++dir) {
            const float* Ap = Apre + (size_t)(l * 2 + dir) * SS * DD + d;
            float Ar[SS];
            #pragma unroll
            for (int s = 0; s < SS; ++s) Ar[s] = Ap[s * DD];
            const float dsk = Dskp[(l * 2 + dir) * DD + d];
            float st[SS];
            #pragma unroll
            for (int s = 0; s < SS; ++s) st[s] = 0.f;
            #pragma unroll
            for (int t8 = 0; t8 < NN; ++t8) {
                const int n = dir ? (NN - 1 - t8) : t8;
                const float dtc = dtv[dir][n];
                const float xv  = xn[n];
                const float dx  = dtc * xv;
                float y = dsk * xv;
                const float* base = &bcres[p * 8 + n][dir * 32];
                #pragma unroll
                for (int s4 = 0; s4 < SS; s4 += 4) {
                    const float4 Bv = *(const float4*)&base[s4];
                    const float4 Cv = *(const float4*)&base[16 + s4];
                    st[s4+0] = fmaf(EXP2(Ar[s4+0] * dtc), st[s4+0], dx * Bv.x);
                    y = fmaf(st[s4+0], Cv.x, y);
                    st[s4+1] = fmaf(EXP2(Ar[s4+1] * dtc), st[s4+1], dx * Bv.y);
                    y = fmaf(st[s4+1], Cv.y, y);
                    st[s4+2] = fmaf(EXP2(Ar[s4+2] * dtc), st[s4+2], dx * Bv.z);
                    y = fmaf(st[s4+2], Cv.z, y);
                    st[s4+3] = fmaf(EXP2(Ar[s4+3] * dtc), st[s4+3], dx * Bv.w);
                    y = fmaf(st[s4+3], Cv.w, y);
                }
                YsU[(p * 8 + n) * 520 + dir * 128 + d] = f2bf(y);
            }
        }
        __syncthreads();                                   // S4

        // ---- P4: MFMA out-projection: C[16x128] = y[16x256] @ outW ----
        {
            s16x8 a[8];
            #pragma unroll
            for (int kc = 0; kc < 8; ++kc)
                a[kc] = *(const s16x8*)&YsU[r16 * 520 + kc * 32 + kg * 8];
            const ushort_t* ol = outWt + l * 32768;
            #pragma unroll
            for (int ti = 0; ti < 2; ++ti) {
                const int col = (wv * 2 + ti) * 16 + r16;
                f32x4 acc = {0.f, 0.f, 0.f, 0.f};
                #pragma unroll
                for (int kc = 0; kc < 8; ++kc) {
                    const s16x8 b = *(const s16x8*)&ol[col * 256 + kc * 32 + kg * 8];
                    acc = __builtin_amdgcn_mfma_f32_16x16x32_bf16(a[kc], b, acc, 0, 0, 0);
                }
                #pragma unroll
                for (int j = 0; j < 4; ++j) pres[kg * 4 + j][col] = acc[j];
            }
        }
        __syncthreads();                                   // S5

        // ---- P5: residual ----
        {
            const float ob = outB[l * DD + d];
            #pragma unroll
            for (int n = 0; n < NN; ++n) h[n] += pres[p * 8 + n][d] + ob;
        }
    }

    // ---- time interpolation + te (precomputed) ----
    const int mc = (m < M) ? m : (M - 1);
    const int bidx = mc / Pb;
    const float tv = t_arr[bidx];
    const float tn = tv * (float)(NN - 1);
    int il = (int)floorf(tn);
    il = il < 0 ? 0 : (il > NN - 2 ? NN - 2 : il);
    const float alpha = tn - (float)il;
    float hlow = 0.f, hhigh = 0.f;
    #pragma unroll
    for (int n = 0; n < NN; ++n) {
        if (n == il)     hlow  = h[n];
        if (n == il + 1) hhigh = h[n];
    }
    float hi = (1.f - alpha) * hlow + alpha * hhigh + te[bidx * DD + d];

    // epilogue buffers overlay arenaB (free after S5): hi2 [2][132] @0, outg [2][16] @264
    float* epi = &arenaB[0][0];
    epi[p * 132 + d] = hi;
    __syncthreads();

    // ---- final 14-wide projection ----
    if (d < GDIM * 8) {
        const int g = d >> 3, j = d & 7;
        float part = 0.f;
        #pragma unroll
        for (int q = 0; q < 16; ++q)
            part = fmaf(epi[p * 132 + j + 8 * q], opW[(j + 8 * q) * GDIM + g], part);
        part += __shfl_xor(part, 4);
        part += __shfl_xor(part, 2);
        part += __shfl_xor(part, 1);
        if (j == 0) epi[264 + p * 16 + g] = part + opB[g];
    }
    __syncthreads();

    // ---- post-process + store ----
    if (d < GDIM && m < M) {
        const int g = d;
        const float v = epi[264 + p * 16 + g];
        float r;
        if (g < 3)        r = v;
        else if (g < 6)   r = softplus_precise(v);
        else if (g < 10) {
            const float q0 = epi[264 + p * 16 + 6], q1 = epi[264 + p * 16 + 7];
            const float q2 = epi[264 + p * 16 + 8], q3 = epi[264 + p * 16 + 9];
            const float nrm = sqrtf(fmaf(q0,q0, fmaf(q1,q1, fmaf(q2,q2, q3*q3))));
            r = v / fmaxf(nrm, 1e-12f);
        } else {
            r = 1.f / (1.f + expf(-v));
        }
        out[(size_t)m * GDIM + g] = r;
    }
}

extern "C" void kernel_launch(void* const* d_in, const int* in_sizes, int n_in,
                              void* d_out, int out_size, void* d_ws, size_t ws_size,
                              hipStream_t stream) {
    const float* xyz   = (const float*)d_in[0];
    const float* scl   = (const float*)d_in[1];
    const float* rotp  = (const float*)d_in[2];
    const float* opa   = (const float*)d_in[3];
    const float* colp  = (const float*)d_in[4];
    const float* t_arr = (const float*)d_in[5];
    const float* tstmp = (const float*)d_in[6];
    const float* inW   = (const float*)d_in[7];
    const float* inB   = (const float*)d_in[8];
    const float* lnG   = (const float*)d_in[9];
    const float* lnB   = (const float*)d_in[10];
    const float* dtW   = (const float*)d_in[11];
    const float* dtB   = (const float*)d_in[12];
    const float* BW    = (const float*)d_in[13];
    const float* CW    = (const float*)d_in[14];
    const float* Alog  = (const float*)d_in[15];
    const float* Dskp  = (const float*)d_in[16];
    const float* outW  = (const float*)d_in[17];
    const float* outB  = (const float*)d_in[18];
    const float* teW1  = (const float*)d_in[19];
    const float* teB1  = (const float*)d_in[20];
    const float* teW2  = (const float*)d_in[21];
    const float* teB2  = (const float*)d_in[22];
    const float* opW   = (const float*)d_in[23];
    const float* opB   = (const float*)d_in[24];

    const int N  = in_sizes[6];            // 8
    const int M  = in_sizes[3] / N;        // B*P
    const int B  = in_sizes[5];
    const int Pb = M / B;
    (void)out_size; (void)n_in;

    ushort_t* wsu = (ushort_t*)d_ws;
    const int prep_elems = WS_USH + WS_AFLT + 1024 + B * 128;
    hipLaunchKernelGGL(prep_weights, dim3((prep_elems + 255) / 256), dim3(256), 0, stream,
                       inW, dtW, BW, CW, outW, Alog, tstmp, inB, t_arr,
                       teW1, teB1, teW2, teB2, B, wsu);
    hipLaunchKernelGGL(ssm_mfma, dim3((M + 1) / 2), dim3(256), 0, stream,
                       xyz, scl, rotp, opa, colp, t_arr,
                       lnG, lnB, dtB, Dskp, outB, opW, opB,
                       wsu, (float*)d_out, M, Pb);
}